// Round 17
// baseline (257.876 us; speedup 1.0000x reference)
//
#include <hip/hip_runtime.h>

#define NS 65536      // stocks
#define HID 512       // hidden
#define NE 128        // industries
#define NEG 0.01f     // LeakyReLU slope

typedef int   vi4 __attribute__((ext_vector_type(4)));
typedef float vf4 __attribute__((ext_vector_type(4)));

// ---------------------------------------------------------------------------
// K1: decode one-hot rows -> ind[s]. Nontemporal vi4 loads.
__global__ __launch_bounds__(1024) void k_find(const int* __restrict__ im,
                                               int* __restrict__ ind) {
    __shared__ int lind[256];
    const int b = blockIdx.x, t = threadIdx.x;
    const vi4* p = reinterpret_cast<const vi4*>(im) + (size_t)b * 8192;
#pragma unroll
    for (int j = t; j < 8192; j += 1024) {   // 256 rows x 32 vi4, 8 iters
        vi4 v = __builtin_nontemporal_load(p + j);
        int s = j >> 5;          // local row
        int c = (j & 31) << 2;   // column of v[0]
        if (v[0] == 1) lind[s] = c;
        if (v[1] == 1) lind[s] = c + 1;
        if (v[2] == 1) lind[s] = c + 2;
        if (v[3] == 1) lind[s] = c + 3;
    }
    __syncthreads();
    if (t < 256) ind[b * 256 + t] = lind[t];
}

// ---------------------------------------------------------------------------
// K2: per-industry row-sum with self-compaction (identical to round 13).
__global__ __launch_bounds__(1024) void k_agg(const float* __restrict__ e_s,
                                              const int* __restrict__ ind,
                                              float* __restrict__ partial,
                                              int* __restrict__ counts) {
    __shared__ int rows[1024];
    __shared__ vf4 red[1024];
    __shared__ int cntL;
    const int e = blockIdx.x >> 2;
    const int q = blockIdx.x & 3;
    const int t = threadIdx.x;
    if (t == 0) cntL = 0;
    __syncthreads();
    const int base = q * (NS / 4);
#pragma unroll
    for (int k = 0; k < (NS / 4) / 1024; ++k) {   // 16 coalesced L2 reads
        int idx = base + k * 1024 + t;
        if (ind[idx] == e) {
            int p = atomicAdd(&cntL, 1);          // LDS atomic append
            if (p < 1024) rows[p] = idx;
        }
    }
    __syncthreads();
    const int cnt = (cntL < 1024) ? cntL : 1024;  // ~128 expected
    const int g = t >> 7;        // 8 row-groups
    const int l = t & 127;       // vf4 column
    vf4 acc = {0.f, 0.f, 0.f, 0.f};
#pragma unroll 4
    for (int i = g; i < cnt; i += 8) {
        int row = rows[i];       // wave-uniform broadcast
        vf4 v = __builtin_nontemporal_load(
            reinterpret_cast<const vf4*>(e_s + (size_t)row * HID) + l);
        acc += v;
    }
    red[t] = acc;
    __syncthreads();
    if (g == 0) {
        vf4 a = red[l];
#pragma unroll
        for (int p = 1; p < 8; ++p) a += red[l + p * 128];
        reinterpret_cast<vf4*>(partial + ((size_t)(q * NE + e)) * HID)[l] = a;
    }
    if (t == 0) counts[q * NE + e] = cnt;
}

// ---------------------------------------------------------------------------
// K3: efrow[e] = LeakyReLU(Binv * (sum_q partial_q[e]) @ W + bias).
// efrow is now a SEPARATE buffer (no overlay) so repeats are idempotent.
__global__ __launch_bounds__(1024) void k_gemm(const float* __restrict__ partial,
                                               const float* __restrict__ W,
                                               const float* __restrict__ bias,
                                               const int* __restrict__ counts,
                                               float* __restrict__ efrow) {
    __shared__ float aL[HID];
    __shared__ float redf[1024];
    const int e = blockIdx.x;
    const int t = threadIdx.x;
    if (t < HID) {
        float s = 0.f;
#pragma unroll
        for (int q = 0; q < 4; ++q) s += partial[((size_t)(q * NE + e)) * HID + t];
        aL[t] = s;
    }
    __syncthreads();
    const int j  = t & (HID - 1);
    const int hh = t >> 9;            // K-half: 0 or 1
    const int k0 = hh * 256;
    float acc = 0.f;
#pragma unroll 8
    for (int k = k0; k < k0 + 256; ++k)
        acc += aL[k] * W[k * HID + j];   // aL: LDS broadcast; W: coalesced/L2
    redf[t] = acc;
    __syncthreads();
    if (t < HID) {
        int tot = counts[e] + counts[NE + e] + counts[2 * NE + e] + counts[3 * NE + e];
        float binv = (tot > 0) ? 1.0f / (float)tot : 0.0f;
        float v = (redf[t] + redf[t + HID]) * binv + bias[t];
        efrow[(size_t)e * HID + t] = (v >= 0.0f) ? v : NEG * v;
    }
}

// ---------------------------------------------------------------------------
// K4: stock-major output. Sequential nontemporal writes.
__global__ __launch_bounds__(1024) void k_out(const float* __restrict__ efrow,
                                              const int* __restrict__ ind,
                                              float* __restrict__ out) {
    __shared__ int lindL[256];
    const int b = blockIdx.x, t = threadIdx.x;
    if (t < 256) lindL[t] = ind[b * 256 + t];
    __syncthreads();
    const int g = t >> 7;        // 8 groups: one stock-row per group per iter
    const int l = t & 127;       // vf4 lane within row
    vf4* outp = reinterpret_cast<vf4*>(out) + (size_t)b * 256 * 128;
#pragma unroll 4
    for (int ls = g; ls < 256; ls += 8) {
        int e = lindL[ls];       // wave-uniform broadcast
        vf4 v = reinterpret_cast<const vf4*>(efrow + (size_t)e * HID)[l];
        __builtin_nontemporal_store(v, outp + ls * 128 + l);
    }
}

extern "C" void kernel_launch(void* const* d_in, const int* in_sizes, int n_in,
                              void* d_out, int out_size, void* d_ws, size_t ws_size,
                              hipStream_t stream) {
    const float* e_s  = (const float*)d_in[0];
    const int*   im   = (const int*)d_in[1];
    const float* W    = (const float*)d_in[2];
    const float* bias = (const float*)d_in[3];
    float* out = (float*)d_out;

    char* ws = (char*)d_ws;
    // layout: ind 256KB @0 | partial 1MB @256K | counts 2KB @1.25MB
    //         | efrow 256KB @1.5MB (separate buffer -> k_gemm idempotent)
    int*   ind     = (int*)(ws + 0);
    float* partial = (float*)(ws + 262144);
    int*   counts  = (int*)(ws + 1310720);
    float* efrow   = (float*)(ws + 1572864);

    // DIAGNOSTIC round: find x5, agg x1, gemm x5, out x5 (all idempotent).
    // find_w + gemm + out = (dur_us - 76.9) / 4.
    k_find<<<256, 1024, 0, stream>>>(im, ind);
    k_find<<<256, 1024, 0, stream>>>(im, ind);
    k_find<<<256, 1024, 0, stream>>>(im, ind);
    k_find<<<256, 1024, 0, stream>>>(im, ind);
    k_find<<<256, 1024, 0, stream>>>(im, ind);
    k_agg <<<NE * 4, 1024, 0, stream>>>(e_s, ind, partial, counts);
    k_gemm<<<NE, 1024, 0, stream>>>(partial, W, bias, counts, efrow);
    k_gemm<<<NE, 1024, 0, stream>>>(partial, W, bias, counts, efrow);
    k_gemm<<<NE, 1024, 0, stream>>>(partial, W, bias, counts, efrow);
    k_gemm<<<NE, 1024, 0, stream>>>(partial, W, bias, counts, efrow);
    k_gemm<<<NE, 1024, 0, stream>>>(partial, W, bias, counts, efrow);
    k_out <<<256, 1024, 0, stream>>>(efrow, ind, out);
    k_out <<<256, 1024, 0, stream>>>(efrow, ind, out);
    k_out <<<256, 1024, 0, stream>>>(efrow, ind, out);
    k_out <<<256, 1024, 0, stream>>>(efrow, ind, out);
    k_out <<<256, 1024, 0, stream>>>(efrow, ind, out);
}

// Round 19
// 81.925 us; speedup vs baseline: 3.1477x; 3.1477x over previous
//
#include <hip/hip_runtime.h>

#define NS 65536      // stocks
#define HID 512       // hidden
#define NE 128        // industries
#define NEG 0.01f     // LeakyReLU slope

typedef int   vi4 __attribute__((ext_vector_type(4)));
typedef float vf4 __attribute__((ext_vector_type(4)));

// ---------------------------------------------------------------------------
// K1: decode one-hot rows -> ind[s]. Plain vi4 loads (NT removed: A/B test).
__global__ __launch_bounds__(1024) void k_find(const int* __restrict__ im,
                                               int* __restrict__ ind) {
    __shared__ int lind[256];
    const int b = blockIdx.x, t = threadIdx.x;
    const vi4* p = reinterpret_cast<const vi4*>(im) + (size_t)b * 8192;
#pragma unroll
    for (int j = t; j < 8192; j += 1024) {   // 256 rows x 32 vi4, 8 iters
        vi4 v = p[j];
        int s = j >> 5;          // local row
        int c = (j & 31) << 2;   // column of v[0]
        if (v[0] == 1) lind[s] = c;
        if (v[1] == 1) lind[s] = c + 1;
        if (v[2] == 1) lind[s] = c + 2;
        if (v[3] == 1) lind[s] = c + 3;
    }
    __syncthreads();
    if (t < 256) ind[b * 256 + t] = lind[t];
}

// ---------------------------------------------------------------------------
// K2: per-industry row-sum with self-compaction. Block = (industry e, quarter q).
// Plain vf4 gather loads (NT removed: A/B test). Otherwise identical to r13.
__global__ __launch_bounds__(1024) void k_agg(const float* __restrict__ e_s,
                                              const int* __restrict__ ind,
                                              float* __restrict__ partial,
                                              int* __restrict__ counts) {
    __shared__ int rows[1024];
    __shared__ vf4 red[1024];
    __shared__ int cntL;
    const int e = blockIdx.x >> 2;
    const int q = blockIdx.x & 3;
    const int t = threadIdx.x;
    if (t == 0) cntL = 0;
    __syncthreads();
    const int base = q * (NS / 4);
#pragma unroll
    for (int k = 0; k < (NS / 4) / 1024; ++k) {   // 16 coalesced L2 reads
        int idx = base + k * 1024 + t;
        if (ind[idx] == e) {
            int p = atomicAdd(&cntL, 1);          // LDS atomic append
            if (p < 1024) rows[p] = idx;
        }
    }
    __syncthreads();
    const int cnt = (cntL < 1024) ? cntL : 1024;  // ~128 expected
    const int g = t >> 7;        // 8 row-groups
    const int l = t & 127;       // vf4 column
    vf4 acc = {0.f, 0.f, 0.f, 0.f};
#pragma unroll 4
    for (int i = g; i < cnt; i += 8) {
        int row = rows[i];       // wave-uniform broadcast
        vf4 v = reinterpret_cast<const vf4*>(e_s + (size_t)row * HID)[l];
        acc += v;
    }
    red[t] = acc;
    __syncthreads();
    if (g == 0) {
        vf4 a = red[l];
#pragma unroll
        for (int p = 1; p < 8; ++p) a += red[l + p * 128];
        reinterpret_cast<vf4*>(partial + ((size_t)(q * NE + e)) * HID)[l] = a;
    }
    if (t == 0) counts[q * NE + e] = cnt;
}

// ---------------------------------------------------------------------------
// K3: efrow[e] = LeakyReLU(Binv * (sum_q partial_q[e]) @ W + bias).
__global__ __launch_bounds__(1024) void k_gemm(const float* __restrict__ partial,
                                               const float* __restrict__ W,
                                               const float* __restrict__ bias,
                                               const int* __restrict__ counts,
                                               float* __restrict__ efrow) {
    __shared__ float aL[HID];
    __shared__ float redf[1024];
    const int e = blockIdx.x;
    const int t = threadIdx.x;
    if (t < HID) {
        float s = 0.f;
#pragma unroll
        for (int q = 0; q < 4; ++q) s += partial[((size_t)(q * NE + e)) * HID + t];
        aL[t] = s;
    }
    __syncthreads();
    const int j  = t & (HID - 1);
    const int hh = t >> 9;            // K-half: 0 or 1
    const int k0 = hh * 256;
    float acc = 0.f;
#pragma unroll 8
    for (int k = k0; k < k0 + 256; ++k)
        acc += aL[k] * W[k * HID + j];   // aL: LDS broadcast; W: coalesced/L2
    redf[t] = acc;
    __syncthreads();
    if (t < HID) {
        int tot = counts[e] + counts[NE + e] + counts[2 * NE + e] + counts[3 * NE + e];
        float binv = (tot > 0) ? 1.0f / (float)tot : 0.0f;
        float v = (redf[t] + redf[t + HID]) * binv + bias[t];
        efrow[(size_t)e * HID + t] = (v >= 0.0f) ? v : NEG * v;
    }
}

// ---------------------------------------------------------------------------
// K4: stock-major output. Plain sequential stores (NT removed: A/B test —
// the harness fills hit 7.15 TB/s with regular stores through L2).
__global__ __launch_bounds__(1024) void k_out(const float* __restrict__ efrow,
                                              const int* __restrict__ ind,
                                              float* __restrict__ out) {
    __shared__ int lindL[256];
    const int b = blockIdx.x, t = threadIdx.x;
    if (t < 256) lindL[t] = ind[b * 256 + t];
    __syncthreads();
    const int g = t >> 7;        // 8 groups: one stock-row per group per iter
    const int l = t & 127;       // vf4 lane within row
    vf4* outp = reinterpret_cast<vf4*>(out) + (size_t)b * 256 * 128;
#pragma unroll 4
    for (int ls = g; ls < 256; ls += 8) {
        int e = lindL[ls];       // wave-uniform broadcast
        vf4 v = reinterpret_cast<const vf4*>(efrow + (size_t)e * HID)[l];
        outp[ls * 128 + l] = v;
    }
}

extern "C" void kernel_launch(void* const* d_in, const int* in_sizes, int n_in,
                              void* d_out, int out_size, void* d_ws, size_t ws_size,
                              hipStream_t stream) {
    const float* e_s  = (const float*)d_in[0];
    const int*   im   = (const int*)d_in[1];
    const float* W    = (const float*)d_in[2];
    const float* bias = (const float*)d_in[3];
    float* out = (float*)d_out;

    char* ws = (char*)d_ws;
    // layout: ind 256KB @0 | partial 1MB @256K | counts 2KB @1.25MB
    //         | efrow 256KB @1.5MB
    int*   ind     = (int*)(ws + 0);
    float* partial = (float*)(ws + 262144);
    int*   counts  = (int*)(ws + 1310720);
    float* efrow   = (float*)(ws + 1572864);

    k_find<<<256, 1024, 0, stream>>>(im, ind);
    k_agg <<<NE * 4, 1024, 0, stream>>>(e_s, ind, partial, counts);
    k_gemm<<<NE, 1024, 0, stream>>>(partial, W, bias, counts, efrow);
    k_out <<<256, 1024, 0, stream>>>(efrow, ind, out);
}